// Round 3
// baseline (318.508 us; speedup 1.0000x reference)
//
#include <hip/hip_runtime.h>

// WARP loss: B=4096 rows, Y=10000 labels, T=128 trials.
// input [B,Y] f32, target [B,Y] f32 (exactly one-hot), neg_candidates [B,T] i32.
// out[0] = sum_rows log((Y-1)/num_trials) * (1 - s_pos + s_neg),
// num_trials = 1 + first t with 1 + s_neg_t - s_pos >= 0 (row skipped if none).

constexpr int Yc    = 10000;
constexpr int Tc    = 128;
constexpr int BLOCK = 256;
constexpr int NV4   = Yc / 4;   // 2500 float4 per row

typedef float f32x4 __attribute__((ext_vector_type(4)));

__global__ __launch_bounds__(BLOCK) void warp_loss_kernel(
        const float* __restrict__ input,
        const float* __restrict__ target,
        const int*   __restrict__ neg,
        float* __restrict__ out) {
    const int    row     = blockIdx.x;
    const int    tid     = threadIdx.x;
    const size_t rowbase = (size_t)row * Yc;

    __shared__ int   sh_pos_idx;   // one-hot index (exactly one writer)
    __shared__ int   sh_first;     // first accepted trial (Tc if none)
    __shared__ float sh_spos;
    __shared__ float sh_cand[Tc];

    // Prefetch candidate scores: independent of the scan, latency overlaps it.
    float s_cand = 0.0f;
    if (tid < Tc) {
        int c  = neg[row * Tc + tid];
        s_cand = input[rowbase + c];
    }

    if (tid == 0) { sh_pos_idx = -1; sh_first = Tc; }
    __syncthreads();

    // ---- one-hot scan with early exit (poll shared flag every 8 KB chunk) ----
    const f32x4* trow = reinterpret_cast<const f32x4*>(target + rowbase);
    for (int base = 0; base < NV4; base += 2 * BLOCK) {
        // Relaxed poll: approximate early exit, wave-uniform branch, no barrier.
        if (__hip_atomic_load(&sh_pos_idx, __ATOMIC_RELAXED,
                              __HIP_MEMORY_SCOPE_WORKGROUP) >= 0) break;
        int  i0 = base + tid;
        int  i1 = i0 + BLOCK;
        bool b0 = i0 < NV4, b1 = i1 < NV4;
        f32x4 v0 = {}, v1 = {};
        if (b0) v0 = __builtin_nontemporal_load(trow + i0);  // streamed once
        if (b1) v1 = __builtin_nontemporal_load(trow + i1);
        int hit = -1;
        if (b0) {
            if (v0[0] > 0.5f) hit = 4 * i0 + 0;
            if (v0[1] > 0.5f) hit = 4 * i0 + 1;
            if (v0[2] > 0.5f) hit = 4 * i0 + 2;
            if (v0[3] > 0.5f) hit = 4 * i0 + 3;
        }
        if (b1) {
            if (v1[0] > 0.5f) hit = 4 * i1 + 0;
            if (v1[1] > 0.5f) hit = 4 * i1 + 1;
            if (v1[2] > 0.5f) hit = 4 * i1 + 2;
            if (v1[3] > 0.5f) hit = 4 * i1 + 3;
        }
        if (hit >= 0)
            __hip_atomic_store(&sh_pos_idx, hit, __ATOMIC_RELAXED,
                               __HIP_MEMORY_SCOPE_WORKGROUP);
    }
    __syncthreads();
    const int pos = sh_pos_idx;           // valid: exactly one positive per row

    // ---- rejection sampling: all testers load s_pos (same addr -> broadcast) ----
    if (tid < Tc) {
        sh_cand[tid] = s_cand;
        float s_pos  = input[rowbase + pos];
        if (tid == 0) sh_spos = s_pos;
        if (1.0f + s_cand - s_pos >= 0.0f) atomicMin(&sh_first, tid);
    }
    __syncthreads();

    if (tid == 0 && sh_first < Tc) {
        int   nt = sh_first + 1;
        float L  = logf((float)((Yc - 1) / nt));   // integer floor-div, then log
        atomicAdd(out, L * (1.0f - sh_spos + sh_cand[sh_first]));
    }
}

extern "C" void kernel_launch(void* const* d_in, const int* in_sizes, int n_in,
                              void* d_out, int out_size, void* d_ws, size_t ws_size,
                              hipStream_t stream) {
    const float* input  = (const float*)d_in[0];
    const float* target = (const float*)d_in[1];
    const int*   neg    = (const int*)d_in[2];
    float* out = (float*)d_out;

    const int B = in_sizes[2] / Tc;  // 4096

    // Harness re-poisons d_out to 0xAA before every timed replay: zero it here.
    hipMemsetAsync(out, 0, sizeof(float), stream);
    warp_loss_kernel<<<B, BLOCK, 0, stream>>>(input, target, neg, out);
}